// Round 2
// baseline (960.039 us; speedup 1.0000x reference)
//
#include <hip/hip_runtime.h>
#include <cstdint>

// ---------------- constants ----------------
#define DM    1024
#define NHEAD 16
#define FFDIM 4096
#define MROWS 16384   // B*N = 8*2048

static constexpr float LAMBDA_INIT_F = 0.3555090675909693f;   // 0.8 - 0.6*exp(-0.3)
static constexpr float ONE_MINUS_LI  = 1.0f - 0.3555090675909693f;
static constexpr float QSCALE        = 0.17677669529663687f;  // 32^-0.5

typedef __attribute__((ext_vector_type(8))) short bf16x8;   // 8 bf16 in 4 VGPRs
typedef __attribute__((ext_vector_type(4))) float f32x4;

__device__ __forceinline__ unsigned short f2bf(float f) {
    union { float f; unsigned int i; } w; w.f = f;
    unsigned int x = w.i;
    return (unsigned short)((x + 0x7fffu + ((x >> 16) & 1u)) >> 16);  // RNE
}
__device__ __forceinline__ float bf2f(unsigned short u) {
    union { unsigned int i; float f; } w; w.i = ((unsigned int)u) << 16; return w.f;
}

// ---------------- f32 -> bf16 weight conversion (n % 1024 == 0) --------------
__global__ __launch_bounds__(256) void cvt_kernel(const float* __restrict__ in,
                                                  unsigned short* __restrict__ out)
{
    const int i = (blockIdx.x * 256 + threadIdx.x) * 4;
    const float4 v = *(const float4*)&in[i];
    ushort4 o;
    o.x = f2bf(v.x); o.y = f2bf(v.y); o.z = f2bf(v.z); o.w = f2bf(v.w);
    *(ushort4*)&out[i] = o;
}

// ---------------- LayerNorm (f32 in, bf16 out): one block / row of 1024 ------
__global__ __launch_bounds__(256) void ln_kernel(const float* __restrict__ xin,
                                                 const float* __restrict__ g,
                                                 const float* __restrict__ b,
                                                 unsigned short* __restrict__ out)
{
    const int row = blockIdx.x;
    const int tid = threadIdx.x;
    const float* xr = xin + (size_t)row * DM;
    float v[4];
    #pragma unroll
    for (int i = 0; i < 4; ++i) v[i] = xr[tid + 256 * i];
    float s1 = v[0] + v[1] + v[2] + v[3];
    float s2 = v[0]*v[0] + v[1]*v[1] + v[2]*v[2] + v[3]*v[3];
    #pragma unroll
    for (int off = 32; off > 0; off >>= 1) {
        s1 += __shfl_down(s1, off);
        s2 += __shfl_down(s2, off);
    }
    __shared__ float red[8];
    const int wv = tid >> 6;
    if ((tid & 63) == 0) { red[wv] = s1; red[4 + wv] = s2; }
    __syncthreads();
    s1 = red[0] + red[1] + red[2] + red[3];
    s2 = red[4] + red[5] + red[6] + red[7];
    const float mean = s1 * (1.0f / DM);
    const float var  = s2 * (1.0f / DM) - mean * mean;
    const float inv  = rsqrtf(var + 1e-5f);
    #pragma unroll
    for (int i = 0; i < 4; ++i) {
        const int c = tid + 256 * i;
        out[(size_t)row * DM + c] = f2bf((v[i] - mean) * inv * g[c] + b[c]);
    }
}

// ---------------- bf16 MFMA GEMM: C[M,N] = A[M,K] * W[N,K]^T (+epilogue) -------
// EPI 0: plain                       -> bf16 out  (QKV)
// EPI 1: + bias(f32) + resid(f32)    -> f32 out   (Wo -> conn)
// EPI 2: + bias(f32) + relu          -> bf16 out  (FFN1)
// EPI 3: + bias(f32) + resid(f32)    -> f32 out   (FFN2 -> d_out)
template<int EPI>
__global__ __launch_bounds__(256) void gemm_bt(const unsigned short* __restrict__ A,
                                               const unsigned short* __restrict__ W,
                                               void* __restrict__ Cout,
                                               const float* __restrict__ bias,
                                               const float* __restrict__ resid,
                                               int M, int N, int K)
{
    constexpr int BM = 128, BN = 128, BK = 32, LDSS = BK + 8;  // +8 pad, keeps 16B align
    __shared__ __align__(16) unsigned short Alds[BM * LDSS];
    __shared__ __align__(16) unsigned short Blds[BN * LDSS];

    const int tid  = threadIdx.x;
    const int lane = tid & 63;
    const int wave = tid >> 6;
    const int l15  = lane & 15;
    const int q4   = lane >> 4;
    const int m0   = blockIdx.y * BM;
    const int n0   = blockIdx.x * BN;
    const int wm   = (wave >> 1) * 64;
    const int wn   = (wave & 1) * 64;

    const f32x4 fzero = {0.f, 0.f, 0.f, 0.f};
    f32x4 acc[4][4];
    #pragma unroll
    for (int i = 0; i < 4; ++i)
        #pragma unroll
        for (int j = 0; j < 4; ++j) acc[i][j] = fzero;

    const int row0 = tid >> 2;        // 0..63
    const int seg  = (tid & 3) * 8;   // 0,8,16,24 (elements)

    for (int k0 = 0; k0 < K; k0 += BK) {
        #pragma unroll
        for (int s = 0; s < 2; ++s) {
            const int row = row0 + s * 64;
            *(uint4*)&Alds[row * LDSS + seg] = *(const uint4*)&A[(size_t)(m0 + row) * K + k0 + seg];
            *(uint4*)&Blds[row * LDSS + seg] = *(const uint4*)&W[(size_t)(n0 + row) * K + k0 + seg];
        }
        __syncthreads();
        bf16x8 af[4], bfr[4];
        #pragma unroll
        for (int i = 0; i < 4; ++i) af[i]  = *(const bf16x8*)&Alds[(wm + i * 16 + l15) * LDSS + q4 * 8];
        #pragma unroll
        for (int j = 0; j < 4; ++j) bfr[j] = *(const bf16x8*)&Blds[(wn + j * 16 + l15) * LDSS + q4 * 8];
        #pragma unroll
        for (int i = 0; i < 4; ++i)
            #pragma unroll
            for (int j = 0; j < 4; ++j)
                acc[i][j] = __builtin_amdgcn_mfma_f32_16x16x32_bf16(af[i], bfr[j], acc[i][j], 0, 0, 0);
        __syncthreads();
    }

    // epilogue: D element (row = q4*4+r, col = l15) within each 16x16 subtile
    #pragma unroll
    for (int i = 0; i < 4; ++i) {
        #pragma unroll
        for (int j = 0; j < 4; ++j) {
            #pragma unroll
            for (int r = 0; r < 4; ++r) {
                const int m = m0 + wm + i * 16 + q4 * 4 + r;
                const int n = n0 + wn + j * 16 + l15;
                const size_t off = (size_t)m * N + n;
                float c = acc[i][j][r];
                if (EPI == 0) {
                    ((unsigned short*)Cout)[off] = f2bf(c);
                } else if (EPI == 1) {
                    c += bias[n] + resid[off];
                    ((float*)Cout)[off] = c;
                } else if (EPI == 2) {
                    c += bias[n];
                    c = fmaxf(c, 0.f);
                    ((unsigned short*)Cout)[off] = f2bf(c);
                } else {
                    c += bias[n] + resid[off];
                    ((float*)Cout)[off] = c;
                }
            }
        }
    }
}

// ---------------- per-position differential attention: 1 wave / token --------
__global__ __launch_bounds__(256) void attn_pos(const unsigned short* __restrict__ qg,
                                                const unsigned short* __restrict__ kg,
                                                const unsigned short* __restrict__ vg,
                                                const float* __restrict__ lq1,
                                                const float* __restrict__ lq2,
                                                const float* __restrict__ lk1,
                                                const float* __restrict__ lk2,
                                                unsigned short* __restrict__ outg)
{
    __shared__ __align__(16) float q2[4][32][36];
    __shared__ __align__(16) float k2[4][32][36];
    __shared__ __align__(16) float v2[4][16][64];
    __shared__ float att2[4][16][17];

    const int tid  = threadIdx.x;
    const int wave = tid >> 6;
    const int lane = tid & 63;
    const int pos  = blockIdx.x * 4 + wave;

    // lambda = exp(sum lq1*lk1) - exp(sum lq2*lk2) + lambda_init  (32-elem dots)
    float s1 = 0.f, s2 = 0.f;
    #pragma unroll
    for (int i = 0; i < 32; ++i) {
        s1 += lq1[i] * lk1[i];
        s2 += lq2[i] * lk2[i];
    }
    const float lam = __expf(s1) - __expf(s2) + LAMBDA_INIT_F;

    const unsigned short* qrow = qg + (size_t)pos * DM;
    const unsigned short* krow = kg + (size_t)pos * DM;
    const unsigned short* vrow = vg + (size_t)pos * DM;

    unsigned short tq[16], tk[16], tv[16];
    *(uint4*)&tq[0] = *(const uint4*)&qrow[lane * 16];
    *(uint4*)&tq[8] = *(const uint4*)&qrow[lane * 16 + 8];
    *(uint4*)&tk[0] = *(const uint4*)&krow[lane * 16];
    *(uint4*)&tk[8] = *(const uint4*)&krow[lane * 16 + 8];
    *(uint4*)&tv[0] = *(const uint4*)&vrow[lane * 16];
    *(uint4*)&tv[8] = *(const uint4*)&vrow[lane * 16 + 8];

    // channel c = h*64 + d*2 + qi  ->  q2[qi*16+h][d];   v: c = h*64+dd -> v2[h][dd]
    #pragma unroll
    for (int jj = 0; jj < 16; ++jj) {
        const int c  = lane * 16 + jj;
        const int h  = c >> 6;
        const int d  = (c >> 1) & 31;
        const int qi = c & 1;
        q2[wave][qi * 16 + h][d] = bf2f(tq[jj]) * QSCALE;
        k2[wave][qi * 16 + h][d] = bf2f(tk[jj]);
        v2[wave][c >> 6][c & 63] = bf2f(tv[jj]);
    }
    __syncthreads();

    // S[qh][kh] = q2[qh,:] . k2[kh,:] ; lane handles row qh=lane&31, kh-half = lane>>5
    const int qh = lane & 31, half = lane >> 5;
    float qreg[32];
    #pragma unroll
    for (int d4 = 0; d4 < 32; d4 += 4) {
        const f32x4 t = *(const f32x4*)&q2[wave][qh][d4];
        qreg[d4] = t[0]; qreg[d4+1] = t[1]; qreg[d4+2] = t[2]; qreg[d4+3] = t[3];
    }
    float p[16];
    #pragma unroll
    for (int jj = 0; jj < 16; ++jj) {
        const float* kr = &k2[wave][half * 16 + jj][0];
        float a = 0.f;
        #pragma unroll
        for (int d4 = 0; d4 < 32; d4 += 4) {
            const f32x4 kv = *(const f32x4*)&kr[d4];
            a += qreg[d4]*kv[0] + qreg[d4+1]*kv[1] + qreg[d4+2]*kv[2] + qreg[d4+3]*kv[3];
        }
        p[jj] = a;
    }

    // softmax over the 32 kh (row split across lane and lane^32)
    float mx = p[0];
    #pragma unroll
    for (int jj = 1; jj < 16; ++jj) mx = fmaxf(mx, p[jj]);
    mx = fmaxf(mx, __shfl_xor(mx, 32));
    float sum = 0.f;
    #pragma unroll
    for (int jj = 0; jj < 16; ++jj) { p[jj] = __expf(p[jj] - mx); sum += p[jj]; }
    sum += __shfl_xor(sum, 32);
    const float inv = 1.0f / sum;

    // att2[a][h] = P[a][h] - lam * P[16+a][16+h]
    if (half == 0 && qh < 16) {
        #pragma unroll
        for (int jj = 0; jj < 16; ++jj) att2[wave][qh][jj] = p[jj] * inv;
    }
    __syncthreads();
    if (half == 1 && qh >= 16) {
        const int a = qh - 16;
        #pragma unroll
        for (int jj = 0; jj < 16; ++jj) att2[wave][a][jj] -= lam * p[jj] * inv;
    }
    __syncthreads();

    // out[a][dd] = sum_h att2[a][h] * v2[h][dd]; lane: a = lane&15, dd block = (lane>>4)*16
    const int a   = lane & 15;
    const int ddb = (lane >> 4) * 16;
    float areg[16];
    #pragma unroll
    for (int h = 0; h < 16; ++h) areg[h] = att2[wave][a][h];
    float o[16];
    #pragma unroll
    for (int j = 0; j < 16; ++j) o[j] = 0.f;
    #pragma unroll
    for (int h = 0; h < 16; ++h) {
        #pragma unroll
        for (int j4 = 0; j4 < 16; j4 += 4) {
            const f32x4 vv = *(const f32x4*)&v2[wave][h][ddb + j4];
            o[j4]   += areg[h] * vv[0];
            o[j4+1] += areg[h] * vv[1];
            o[j4+2] += areg[h] * vv[2];
            o[j4+3] += areg[h] * vv[3];
        }
    }

    // rmsnorm over dd(64): combine partial sums across the 4 lanes sharing `a`
    float ss = 0.f;
    #pragma unroll
    for (int j = 0; j < 16; ++j) ss += o[j] * o[j];
    ss += __shfl_xor(ss, 16);
    ss += __shfl_xor(ss, 32);
    const float scl = rsqrtf(ss * (1.0f / 64.0f) + 1e-5f) * ONE_MINUS_LI;

    unsigned short ob[16];
    #pragma unroll
    for (int j = 0; j < 16; ++j) ob[j] = f2bf(o[j] * scl);
    unsigned short* orow = outg + (size_t)pos * DM + a * 64 + ddb;
    *(uint4*)&orow[0] = *(const uint4*)&ob[0];
    *(uint4*)&orow[8] = *(const uint4*)&ob[8];
}

// ---------------- launcher ----------------
extern "C" void kernel_launch(void* const* d_in, const int* in_sizes, int n_in,
                              void* d_out, int out_size, void* d_ws, size_t ws_size,
                              hipStream_t stream)
{
    const float* x   = (const float*)d_in[0];
    const float* Wq  = (const float*)d_in[1];
    const float* Wk  = (const float*)d_in[2];
    const float* Wv  = (const float*)d_in[3];
    const float* lq1 = (const float*)d_in[4];
    const float* lq2 = (const float*)d_in[5];
    const float* lk1 = (const float*)d_in[6];
    const float* lk2 = (const float*)d_in[7];
    const float* Wo  = (const float*)d_in[8];
    const float* bo  = (const float*)d_in[9];
    const float* g1  = (const float*)d_in[10];
    const float* be1 = (const float*)d_in[11];
    const float* g2  = (const float*)d_in[12];
    const float* be2 = (const float*)d_in[13];
    const float* W1  = (const float*)d_in[14];
    const float* b1  = (const float*)d_in[15];
    const float* W2  = (const float*)d_in[16];
    const float* b2  = (const float*)d_in[17];
    (void)in_sizes; (void)n_in; (void)out_size;

    const size_t MB = 1ull << 20;
    char* ws = (char*)d_ws;
    // bf16 weights: Wq,Wk,Wv,Wo (2 MB each), W1,W2 (8 MB each) = 24 MB
    unsigned short* wq = (unsigned short*)(ws);
    unsigned short* wk = (unsigned short*)(ws + 2 * MB);
    unsigned short* wv = (unsigned short*)(ws + 4 * MB);
    unsigned short* wo = (unsigned short*)(ws + 6 * MB);
    unsigned short* w1 = (unsigned short*)(ws + 8 * MB);
    unsigned short* w2 = (unsigned short*)(ws + 16 * MB);
    unsigned short* h    = (unsigned short*)(ws + 24 * MB);   // 32 MB bf16, reused as attn-out
    unsigned short* q    = (unsigned short*)(ws + 56 * MB);   // 32 MB
    unsigned short* k    = (unsigned short*)(ws + 88 * MB);   // 32 MB
    unsigned short* v    = (unsigned short*)(ws + 120 * MB);  // 32 MB
    float*          conn = (float*)(ws + 56 * MB);            // 64 MB f32, over q+k (dead)
    unsigned short* attn = h;                                 // over h (dead)
    unsigned short* h2   = (unsigned short*)(ws + 120 * MB);  // over v (dead)
    unsigned short* t    = (unsigned short*)(ws + 152 * MB);  // FFN intermediate (chunked)

    // adaptive FFN chunking so we never exceed ws_size
    int nch = 1;
    while (nch < 128 && 152 * MB + (size_t)(MROWS / nch) * FFDIM * 2 > ws_size) nch <<= 1;
    const int MC = MROWS / nch;

    const dim3 blk(256);
    const dim3 gDM(DM / 128, MROWS / 128);     // (8,128)

    // weight conversion (f32 -> bf16)
    cvt_kernel<<<DM * DM / 1024, blk, 0, stream>>>(Wq, wq);
    cvt_kernel<<<DM * DM / 1024, blk, 0, stream>>>(Wk, wk);
    cvt_kernel<<<DM * DM / 1024, blk, 0, stream>>>(Wv, wv);
    cvt_kernel<<<DM * DM / 1024, blk, 0, stream>>>(Wo, wo);
    cvt_kernel<<<FFDIM * DM / 1024, blk, 0, stream>>>(W1, w1);
    cvt_kernel<<<FFDIM * DM / 1024, blk, 0, stream>>>(W2, w2);

    ln_kernel<<<MROWS, blk, 0, stream>>>(x, g1, be1, h);

    gemm_bt<0><<<gDM, blk, 0, stream>>>(h, wq, q, nullptr, nullptr, MROWS, DM, DM);
    gemm_bt<0><<<gDM, blk, 0, stream>>>(h, wk, k, nullptr, nullptr, MROWS, DM, DM);
    gemm_bt<0><<<gDM, blk, 0, stream>>>(h, wv, v, nullptr, nullptr, MROWS, DM, DM);

    attn_pos<<<MROWS / 4, blk, 0, stream>>>(q, k, v, lq1, lq2, lk1, lk2, attn);

    gemm_bt<1><<<gDM, blk, 0, stream>>>(attn, wo, conn, bo, x, MROWS, DM, DM);

    ln_kernel<<<MROWS, blk, 0, stream>>>(conn, g2, be2, h2);

    for (int c = 0; c < nch; ++c) {
        const size_t roff = (size_t)c * MC;
        gemm_bt<2><<<dim3(FFDIM / 128, MC / 128), blk, 0, stream>>>(
            h2 + roff * DM, w1, t, b1, nullptr, MC, FFDIM, DM);
        gemm_bt<3><<<dim3(DM / 128, MC / 128), blk, 0, stream>>>(
            t, w2, (float*)d_out + roff * DM, b2, conn + roff * DM, MC, DM, FFDIM);
    }
}

// Round 3
// 878.244 us; speedup vs baseline: 1.0931x; 1.0931x over previous
//
#include <hip/hip_runtime.h>
#include <cstdint>

// ---------------- constants ----------------
#define DM    1024
#define NHEAD 16
#define FFDIM 4096
#define MROWS 16384   // B*N = 8*2048

static constexpr float LAMBDA_INIT_F = 0.3555090675909693f;   // 0.8 - 0.6*exp(-0.3)
static constexpr float ONE_MINUS_LI  = 1.0f - 0.3555090675909693f;
static constexpr float QSCALE        = 0.17677669529663687f;  // 32^-0.5

typedef __attribute__((ext_vector_type(8))) short bf16x8;   // 8 bf16 in 4 VGPRs
typedef __attribute__((ext_vector_type(4))) float f32x4;

__device__ __forceinline__ unsigned short f2bf(float f) {
    union { float f; unsigned int i; } w; w.f = f;
    unsigned int x = w.i;
    return (unsigned short)((x + 0x7fffu + ((x >> 16) & 1u)) >> 16);  // RNE
}
__device__ __forceinline__ float bf2f(unsigned short u) {
    union { unsigned int i; float f; } w; w.i = ((unsigned int)u) << 16; return w.f;
}

// async global(16B/lane) -> LDS(base + lane*16B); m97 rung of the ladder
__device__ __forceinline__ void load_lds16(const void* gptr, void* lptr) {
    __builtin_amdgcn_global_load_lds(
        (const __attribute__((address_space(1))) unsigned int*)gptr,
        (__attribute__((address_space(3))) unsigned int*)lptr, 16, 0, 0);
}

// ---------------- f32 -> bf16 conversion (n % 1024 == 0) ---------------------
__global__ __launch_bounds__(256) void cvt_kernel(const float* __restrict__ in,
                                                  unsigned short* __restrict__ out)
{
    const int i = (blockIdx.x * 256 + threadIdx.x) * 4;
    const float4 v = *(const float4*)&in[i];
    ushort4 o;
    o.x = f2bf(v.x); o.y = f2bf(v.y); o.z = f2bf(v.z); o.w = f2bf(v.w);
    *(ushort4*)&out[i] = o;
}

// ---------------- LayerNorm (f32 in, bf16 out): one block / row of 1024 ------
__global__ __launch_bounds__(256) void ln_kernel(const float* __restrict__ xin,
                                                 const float* __restrict__ g,
                                                 const float* __restrict__ b,
                                                 unsigned short* __restrict__ out)
{
    const int row = blockIdx.x;
    const int tid = threadIdx.x;
    const float* xr = xin + (size_t)row * DM;
    float v[4];
    #pragma unroll
    for (int i = 0; i < 4; ++i) v[i] = xr[tid + 256 * i];
    float s1 = v[0] + v[1] + v[2] + v[3];
    float s2 = v[0]*v[0] + v[1]*v[1] + v[2]*v[2] + v[3]*v[3];
    #pragma unroll
    for (int off = 32; off > 0; off >>= 1) {
        s1 += __shfl_down(s1, off);
        s2 += __shfl_down(s2, off);
    }
    __shared__ float red[8];
    const int wv = tid >> 6;
    if ((tid & 63) == 0) { red[wv] = s1; red[4 + wv] = s2; }
    __syncthreads();
    s1 = red[0] + red[1] + red[2] + red[3];
    s2 = red[4] + red[5] + red[6] + red[7];
    const float mean = s1 * (1.0f / DM);
    const float var  = s2 * (1.0f / DM) - mean * mean;
    const float inv  = rsqrtf(var + 1e-5f);
    #pragma unroll
    for (int i = 0; i < 4; ++i) {
        const int c = tid + 256 * i;
        out[(size_t)row * DM + c] = f2bf((v[i] - mean) * inv * g[c] + b[c]);
    }
}

// ---------------- bf16 MFMA GEMM (m97 structure): C = A[M,K] * W[N,K]^T -------
// EPI 0: plain                    -> bf16 out  (QKV fused)
// EPI 1: + bias(f32) + resid(f32) -> f32 out   (Wo -> conn)
// EPI 2: + bias(f32) + relu       -> bf16 out  (FFN1)
// EPI 3: + bias(f32) + resid(f32) -> f32 out   (FFN2 -> d_out)
template<int EPI>
__global__ __launch_bounds__(256) void gemm_bt(const unsigned short* __restrict__ A,
                                               const unsigned short* __restrict__ W,
                                               void* __restrict__ Cout,
                                               const float* __restrict__ bias,
                                               const float* __restrict__ resid,
                                               int M, int N, int K)
{
    constexpr int BM = 128, BN = 128, BK = 32;
    __shared__ __align__(16) unsigned short Alds[BM * BK];   // unpadded: global_load_lds layout
    __shared__ __align__(16) unsigned short Blds[BN * BK];

    const int tid  = threadIdx.x;
    const int lane = tid & 63;
    const int wave = tid >> 6;
    const int l15  = lane & 15;
    const int q4   = lane >> 4;
    const int m0   = blockIdx.y * BM;
    const int n0   = blockIdx.x * BN;
    const int wm   = (wave >> 1) * 64;
    const int wn   = (wave & 1) * 64;

    const f32x4 fzero = {0.f, 0.f, 0.f, 0.f};
    f32x4 acc[4][4];
    #pragma unroll
    for (int i = 0; i < 4; ++i)
        #pragma unroll
        for (int j = 0; j < 4; ++j) acc[i][j] = fzero;

    // staging: wave w covers rows [32w, 32w+32) of both tiles; lane l -> 16 B at
    // row 32w + (l>>2), col (l&3)*8  ==  LDS byte (32w*64) + l*16  (lane-ordered)
    const int rseg = lane >> 2;
    const int cseg = (lane & 3) * 8;
    const unsigned short* ga = A + (size_t)(m0 + wave * 32 + rseg) * K + cseg;
    const unsigned short* gb = W + (size_t)(n0 + wave * 32 + rseg) * K + cseg;
    unsigned short* la0 = &Alds[wave * 32 * BK];
    unsigned short* lb0 = &Blds[wave * 32 * BK];

    for (int k0 = 0; k0 < K; k0 += BK) {
        load_lds16(ga,           la0);
        load_lds16(ga + 16 * K,  la0 + 16 * BK);
        load_lds16(gb,           lb0);
        load_lds16(gb + 16 * K,  lb0 + 16 * BK);
        ga += BK; gb += BK;
        __syncthreads();                       // drains vmcnt -> tiles ready
        bf16x8 af[4], bfr[4];
        #pragma unroll
        for (int i = 0; i < 4; ++i) af[i]  = *(const bf16x8*)&Alds[(wm + i * 16 + l15) * BK + q4 * 8];
        #pragma unroll
        for (int j = 0; j < 4; ++j) bfr[j] = *(const bf16x8*)&Blds[(wn + j * 16 + l15) * BK + q4 * 8];
        #pragma unroll
        for (int i = 0; i < 4; ++i)
            #pragma unroll
            for (int j = 0; j < 4; ++j)
                acc[i][j] = __builtin_amdgcn_mfma_f32_16x16x32_bf16(af[i], bfr[j], acc[i][j], 0, 0, 0);
        __syncthreads();                       // all ds_reads done before re-staging
    }

    // epilogue: D element (row = q4*4+r, col = l15) within each 16x16 subtile
    #pragma unroll
    for (int i = 0; i < 4; ++i) {
        #pragma unroll
        for (int j = 0; j < 4; ++j) {
            #pragma unroll
            for (int r = 0; r < 4; ++r) {
                const int m = m0 + wm + i * 16 + q4 * 4 + r;
                const int n = n0 + wn + j * 16 + l15;
                const size_t off = (size_t)m * N + n;
                float c = acc[i][j][r];
                if (EPI == 0) {
                    ((unsigned short*)Cout)[off] = f2bf(c);
                } else if (EPI == 1) {
                    c += bias[n] + resid[off];
                    ((float*)Cout)[off] = c;
                } else if (EPI == 2) {
                    c += bias[n];
                    c = fmaxf(c, 0.f);
                    ((unsigned short*)Cout)[off] = f2bf(c);
                } else {
                    c += bias[n] + resid[off];
                    ((float*)Cout)[off] = c;
                }
            }
        }
    }
}

// ---------------- per-position differential attention: 1 wave / token --------
// q/k/v are views into the fused qkv buffer with row stride QKVS
#define QKVS 3072
__global__ __launch_bounds__(256) void attn_pos(const unsigned short* __restrict__ qkv,
                                                const float* __restrict__ lq1,
                                                const float* __restrict__ lq2,
                                                const float* __restrict__ lk1,
                                                const float* __restrict__ lk2,
                                                unsigned short* __restrict__ outg)
{
    __shared__ __align__(16) float q2[4][32][36];
    __shared__ __align__(16) float k2[4][32][36];
    __shared__ __align__(16) float v2[4][16][64];
    __shared__ float att2[4][16][17];

    const int tid  = threadIdx.x;
    const int wave = tid >> 6;
    const int lane = tid & 63;
    const int pos  = blockIdx.x * 4 + wave;

    float s1 = 0.f, s2 = 0.f;
    #pragma unroll
    for (int i = 0; i < 32; ++i) {
        s1 += lq1[i] * lk1[i];
        s2 += lq2[i] * lk2[i];
    }
    const float lam = __expf(s1) - __expf(s2) + LAMBDA_INIT_F;

    const unsigned short* qrow = qkv + (size_t)pos * QKVS;
    const unsigned short* krow = qrow + DM;
    const unsigned short* vrow = qrow + 2 * DM;

    unsigned short tq[16], tk[16], tv[16];
    *(uint4*)&tq[0] = *(const uint4*)&qrow[lane * 16];
    *(uint4*)&tq[8] = *(const uint4*)&qrow[lane * 16 + 8];
    *(uint4*)&tk[0] = *(const uint4*)&krow[lane * 16];
    *(uint4*)&tk[8] = *(const uint4*)&krow[lane * 16 + 8];
    *(uint4*)&tv[0] = *(const uint4*)&vrow[lane * 16];
    *(uint4*)&tv[8] = *(const uint4*)&vrow[lane * 16 + 8];

    // channel c = h*64 + d*2 + qi -> q2[qi*16+h][d];  v: c = h*64+dd -> v2[h][dd]
    #pragma unroll
    for (int jj = 0; jj < 16; ++jj) {
        const int c  = lane * 16 + jj;
        const int h  = c >> 6;
        const int d  = (c >> 1) & 31;
        const int qi = c & 1;
        q2[wave][qi * 16 + h][d] = bf2f(tq[jj]) * QSCALE;
        k2[wave][qi * 16 + h][d] = bf2f(tk[jj]);
        v2[wave][c >> 6][c & 63] = bf2f(tv[jj]);
    }
    __syncthreads();

    const int qh = lane & 31, half = lane >> 5;
    float qreg[32];
    #pragma unroll
    for (int d4 = 0; d4 < 32; d4 += 4) {
        const f32x4 t = *(const f32x4*)&q2[wave][qh][d4];
        qreg[d4] = t[0]; qreg[d4+1] = t[1]; qreg[d4+2] = t[2]; qreg[d4+3] = t[3];
    }
    float p[16];
    #pragma unroll
    for (int jj = 0; jj < 16; ++jj) {
        const float* kr = &k2[wave][half * 16 + jj][0];
        float a = 0.f;
        #pragma unroll
        for (int d4 = 0; d4 < 32; d4 += 4) {
            const f32x4 kv = *(const f32x4*)&kr[d4];
            a += qreg[d4]*kv[0] + qreg[d4+1]*kv[1] + qreg[d4+2]*kv[2] + qreg[d4+3]*kv[3];
        }
        p[jj] = a;
    }

    float mx = p[0];
    #pragma unroll
    for (int jj = 1; jj < 16; ++jj) mx = fmaxf(mx, p[jj]);
    mx = fmaxf(mx, __shfl_xor(mx, 32));
    float sum = 0.f;
    #pragma unroll
    for (int jj = 0; jj < 16; ++jj) { p[jj] = __expf(p[jj] - mx); sum += p[jj]; }
    sum += __shfl_xor(sum, 32);
    const float inv = 1.0f / sum;

    if (half == 0 && qh < 16) {
        #pragma unroll
        for (int jj = 0; jj < 16; ++jj) att2[wave][qh][jj] = p[jj] * inv;
    }
    __syncthreads();
    if (half == 1 && qh >= 16) {
        const int a = qh - 16;
        #pragma unroll
        for (int jj = 0; jj < 16; ++jj) att2[wave][a][jj] -= lam * p[jj] * inv;
    }
    __syncthreads();

    const int a   = lane & 15;
    const int ddb = (lane >> 4) * 16;
    float areg[16];
    #pragma unroll
    for (int h = 0; h < 16; ++h) areg[h] = att2[wave][a][h];
    float o[16];
    #pragma unroll
    for (int j = 0; j < 16; ++j) o[j] = 0.f;
    #pragma unroll
    for (int h = 0; h < 16; ++h) {
        #pragma unroll
        for (int j4 = 0; j4 < 16; j4 += 4) {
            const f32x4 vv = *(const f32x4*)&v2[wave][h][ddb + j4];
            o[j4]   += areg[h] * vv[0];
            o[j4+1] += areg[h] * vv[1];
            o[j4+2] += areg[h] * vv[2];
            o[j4+3] += areg[h] * vv[3];
        }
    }

    float ss = 0.f;
    #pragma unroll
    for (int j = 0; j < 16; ++j) ss += o[j] * o[j];
    ss += __shfl_xor(ss, 16);
    ss += __shfl_xor(ss, 32);
    const float scl = rsqrtf(ss * (1.0f / 64.0f) + 1e-5f) * ONE_MINUS_LI;

    unsigned short ob[16];
    #pragma unroll
    for (int j = 0; j < 16; ++j) ob[j] = f2bf(o[j] * scl);
    unsigned short* orow = outg + (size_t)pos * DM + a * 64 + ddb;
    *(uint4*)&orow[0] = *(const uint4*)&ob[0];
    *(uint4*)&orow[8] = *(const uint4*)&ob[8];
}

// ---------------- launcher ----------------
extern "C" void kernel_launch(void* const* d_in, const int* in_sizes, int n_in,
                              void* d_out, int out_size, void* d_ws, size_t ws_size,
                              hipStream_t stream)
{
    const float* x   = (const float*)d_in[0];
    const float* Wq  = (const float*)d_in[1];
    const float* Wk  = (const float*)d_in[2];
    const float* Wv  = (const float*)d_in[3];
    const float* lq1 = (const float*)d_in[4];
    const float* lq2 = (const float*)d_in[5];
    const float* lk1 = (const float*)d_in[6];
    const float* lk2 = (const float*)d_in[7];
    const float* Wo  = (const float*)d_in[8];
    const float* bo  = (const float*)d_in[9];
    const float* g1  = (const float*)d_in[10];
    const float* be1 = (const float*)d_in[11];
    const float* g2  = (const float*)d_in[12];
    const float* be2 = (const float*)d_in[13];
    const float* W1  = (const float*)d_in[14];
    const float* b1  = (const float*)d_in[15];
    const float* W2  = (const float*)d_in[16];
    const float* b2  = (const float*)d_in[17];
    (void)in_sizes; (void)n_in; (void)out_size;

    const size_t MB = 1ull << 20;
    char* ws = (char*)d_ws;
    unsigned short* wqkv = (unsigned short*)(ws);             //  6 MB  [3072][1024] bf16
    unsigned short* wo   = (unsigned short*)(ws + 6 * MB);    //  2 MB
    unsigned short* w1   = (unsigned short*)(ws + 8 * MB);    //  8 MB
    unsigned short* w2   = (unsigned short*)(ws + 16 * MB);   //  8 MB
    unsigned short* h    = (unsigned short*)(ws + 24 * MB);   // 32 MB bf16, reused as attn-out
    unsigned short* qkv  = (unsigned short*)(ws + 56 * MB);   // 96 MB bf16 [16384][3072]
    float*          conn = (float*)(ws + 56 * MB);            // 64 MB f32 (over qkv, dead)
    unsigned short* attn = h;                                 // over h (dead)
    unsigned short* h2   = (unsigned short*)(ws + 120 * MB);  // 32 MB (over qkv tail, dead)
    unsigned short* t    = (unsigned short*)(ws + 152 * MB);  // FFN intermediate (chunked)

    int nch = 1;
    while (nch < 128 && 152 * MB + (size_t)(MROWS / nch) * FFDIM * 2 > ws_size) nch <<= 1;
    const int MC = MROWS / nch;

    const dim3 blk(256);

    // pack W_q|W_k|W_v -> wqkv (bf16), plus wo/w1/w2
    cvt_kernel<<<DM * DM / 1024, blk, 0, stream>>>(Wq, wqkv);
    cvt_kernel<<<DM * DM / 1024, blk, 0, stream>>>(Wk, wqkv + DM * DM);
    cvt_kernel<<<DM * DM / 1024, blk, 0, stream>>>(Wv, wqkv + 2 * DM * DM);
    cvt_kernel<<<DM * DM / 1024, blk, 0, stream>>>(Wo, wo);
    cvt_kernel<<<FFDIM * DM / 1024, blk, 0, stream>>>(W1, w1);
    cvt_kernel<<<FFDIM * DM / 1024, blk, 0, stream>>>(W2, w2);

    ln_kernel<<<MROWS, blk, 0, stream>>>(x, g1, be1, h);

    gemm_bt<0><<<dim3(QKVS / 128, MROWS / 128), blk, 0, stream>>>(
        h, wqkv, qkv, nullptr, nullptr, MROWS, QKVS, DM);

    attn_pos<<<MROWS / 4, blk, 0, stream>>>(qkv, lq1, lq2, lk1, lk2, attn);

    gemm_bt<1><<<dim3(DM / 128, MROWS / 128), blk, 0, stream>>>(
        attn, wo, conn, bo, x, MROWS, DM, DM);

    ln_kernel<<<MROWS, blk, 0, stream>>>(conn, g2, be2, h2);

    for (int c = 0; c < nch; ++c) {
        const size_t roff = (size_t)c * MC;
        gemm_bt<2><<<dim3(FFDIM / 128, MC / 128), blk, 0, stream>>>(
            h2 + roff * DM, w1, t, b1, nullptr, MC, FFDIM, DM);
        gemm_bt<3><<<dim3(DM / 128, MC / 128), blk, 0, stream>>>(
            t, w2, (float*)d_out + roff * DM, b2, conn + roff * DM, MC, DM, FFDIM);
    }
}

// Round 4
// 813.711 us; speedup vs baseline: 1.1798x; 1.0793x over previous
//
#include <hip/hip_runtime.h>
#include <cstdint>

// ---------------- constants ----------------
#define DM    1024
#define NHEAD 16
#define FFDIM 4096
#define MROWS 16384   // B*N = 8*2048

static constexpr float LAMBDA_INIT_F = 0.3555090675909693f;   // 0.8 - 0.6*exp(-0.3)
static constexpr float ONE_MINUS_LI  = 1.0f - 0.3555090675909693f;
static constexpr float QSCALE        = 0.17677669529663687f;  // 32^-0.5

typedef __attribute__((ext_vector_type(8))) short bf16x8;   // 8 bf16 in 4 VGPRs
typedef __attribute__((ext_vector_type(4))) float f32x4;

__device__ __forceinline__ unsigned short f2bf(float f) {
    union { float f; unsigned int i; } w; w.f = f;
    unsigned int x = w.i;
    return (unsigned short)((x + 0x7fffu + ((x >> 16) & 1u)) >> 16);  // RNE
}
__device__ __forceinline__ float bf2f(unsigned short u) {
    union { unsigned int i; float f; } w; w.i = ((unsigned int)u) << 16; return w.f;
}

// async global(16B/lane) -> LDS(base + lane*16B)
__device__ __forceinline__ void load_lds16(const void* gptr, void* lptr) {
    __builtin_amdgcn_global_load_lds(
        (const __attribute__((address_space(1))) unsigned int*)gptr,
        (__attribute__((address_space(3))) unsigned int*)lptr, 16, 0, 0);
}

// ---------------- fused f32 -> bf16 weight conversion ------------------------
// block ranges: [0,1024) Wq | [1024,2048) Wk | [2048,3072) Wv | [3072,4096) Wo
//               [4096,8192) W1 | [8192,12288) W2.  1024 f32 per block.
__global__ __launch_bounds__(256) void cvt6_kernel(const float* __restrict__ Wq,
                                                   const float* __restrict__ Wk,
                                                   const float* __restrict__ Wv,
                                                   const float* __restrict__ Wo,
                                                   const float* __restrict__ W1,
                                                   const float* __restrict__ W2,
                                                   unsigned short* __restrict__ wqkv,
                                                   unsigned short* __restrict__ wo,
                                                   unsigned short* __restrict__ w1,
                                                   unsigned short* __restrict__ w2)
{
    const int b = blockIdx.x;
    const float* src;
    unsigned short* dst;
    int off;
    if (b < 3072)      { src = (b < 1024) ? Wq : (b < 2048) ? Wk : Wv;
                         dst = wqkv + (b >> 10) * (DM * DM);
                         off = (b & 1023) * 1024; }
    else if (b < 4096) { src = Wo; dst = wo; off = (b - 3072) * 1024; }
    else if (b < 8192) { src = W1; dst = w1; off = (b - 4096) * 1024; }
    else               { src = W2; dst = w2; off = (b - 8192) * 1024; }
    const int i = off + threadIdx.x * 4;
    const float4 v = *(const float4*)&src[i];
    ushort4 o;
    o.x = f2bf(v.x); o.y = f2bf(v.y); o.z = f2bf(v.z); o.w = f2bf(v.w);
    *(ushort4*)&dst[i] = o;
}

// ---------------- LayerNorm (f32 in, bf16 out): one block / row of 1024 ------
__global__ __launch_bounds__(256) void ln_kernel(const float* __restrict__ xin,
                                                 const float* __restrict__ g,
                                                 const float* __restrict__ b,
                                                 unsigned short* __restrict__ out)
{
    const int row = blockIdx.x;
    const int tid = threadIdx.x;
    const float* xr = xin + (size_t)row * DM;
    float v[4];
    #pragma unroll
    for (int i = 0; i < 4; ++i) v[i] = xr[tid + 256 * i];
    float s1 = v[0] + v[1] + v[2] + v[3];
    float s2 = v[0]*v[0] + v[1]*v[1] + v[2]*v[2] + v[3]*v[3];
    #pragma unroll
    for (int off = 32; off > 0; off >>= 1) {
        s1 += __shfl_down(s1, off);
        s2 += __shfl_down(s2, off);
    }
    __shared__ float red[8];
    const int wv = tid >> 6;
    if ((tid & 63) == 0) { red[wv] = s1; red[4 + wv] = s2; }
    __syncthreads();
    s1 = red[0] + red[1] + red[2] + red[3];
    s2 = red[4] + red[5] + red[6] + red[7];
    const float mean = s1 * (1.0f / DM);
    const float var  = s2 * (1.0f / DM) - mean * mean;
    const float inv  = rsqrtf(var + 1e-5f);
    #pragma unroll
    for (int i = 0; i < 4; ++i) {
        const int c = tid + 256 * i;
        out[(size_t)row * DM + c] = f2bf((v[i] - mean) * inv * g[c] + b[c]);
    }
}

// ---------------- bf16 MFMA GEMM: BK=64, XOR-swizzled LDS --------------------
// C = A[M,K] * W[N,K]^T (+epilogue).
// LDS layout rule (per 32-row slab, row stride 128 B): element block (row R,
// col-group g of 8 elems) lives at byte R*128 + ((g ^ (R&7))*16).  This is
// exactly what global_load_lds's rigid lane->base+16*lane mapping produces
// when lane l fetches global (row = l/8, colgrp = (l%8)^(l/8)).
// EPI 0: plain                    -> bf16 out  (QKV fused)
// EPI 1: + bias(f32) + resid(f32) -> f32 out   (Wo -> conn)
// EPI 2: + bias(f32) + relu       -> bf16 out  (FFN1)
// EPI 3: + bias(f32) + resid(f32) -> f32 out   (FFN2 -> d_out)
template<int EPI>
__global__ __launch_bounds__(256) void gemm_bt(const unsigned short* __restrict__ A,
                                               const unsigned short* __restrict__ W,
                                               void* __restrict__ Cout,
                                               const float* __restrict__ bias,
                                               const float* __restrict__ resid,
                                               int M, int N, int K)
{
    constexpr int BM = 128, BN = 128, BK = 64;
    constexpr int G = BK / 8;     // 8 col-groups per row
    __shared__ __align__(16) unsigned short Alds[BM * BK];   // 16 KB
    __shared__ __align__(16) unsigned short Blds[BN * BK];   // 16 KB

    const int tid  = threadIdx.x;
    const int lane = tid & 63;
    const int wave = tid >> 6;
    const int l15  = lane & 15;
    const int q4   = lane >> 4;
    const int m0   = blockIdx.y * BM;
    const int n0   = blockIdx.x * BN;
    const int wm   = (wave >> 1) * 64;
    const int wn   = (wave & 1) * 64;

    const f32x4 fzero = {0.f, 0.f, 0.f, 0.f};
    f32x4 acc[4][4];
    #pragma unroll
    for (int i = 0; i < 4; ++i)
        #pragma unroll
        for (int j = 0; j < 4; ++j) acc[i][j] = fzero;

    // staging addresses: lane l -> row (within wave's 32-row slab) rL = l/8,
    // swizzled col-group gsw = (l%8) ^ (l/8); 4 chunks of 8 rows per operand.
    const int rL  = lane >> 3;                 // 0..7
    const int gsw = (lane & 7) ^ (rL & (G-1)); // 0..7
    const unsigned short* ga = A + (size_t)(m0 + wave * 32 + rL) * K + gsw * 8;
    const unsigned short* gb = W + (size_t)(n0 + wave * 32 + rL) * K + gsw * 8;
    unsigned short* la0 = &Alds[wave * 32 * BK];
    unsigned short* lb0 = &Blds[wave * 32 * BK];

    // swizzled fragment-read column offset: g = kk*4 + q4, XOR (row & 7).
    // row = wm/wn + i*16 + l15 => row&7 == l15&7 (wm, i*16 are mult. of 8/16).
    const int sa = q4 ^ (l15 & 7);             // kk=0 col-group; kk=1 is sa^4

    for (int k0 = 0; k0 < K; k0 += BK) {
        #pragma unroll
        for (int c = 0; c < 4; ++c) {
            load_lds16(ga + (size_t)(c * 8) * K, la0 + c * 8 * BK);
            load_lds16(gb + (size_t)(c * 8) * K, lb0 + c * 8 * BK);
        }
        ga += BK; gb += BK;
        __syncthreads();                       // drains vmcnt -> tiles ready
        #pragma unroll
        for (int kk = 0; kk < 2; ++kk) {
            const int goff = ((kk == 0) ? sa : (sa ^ 4)) * 8;
            bf16x8 af[4], bfr[4];
            #pragma unroll
            for (int i = 0; i < 4; ++i) af[i]  = *(const bf16x8*)&Alds[(wm + i * 16 + l15) * BK + goff];
            #pragma unroll
            for (int j = 0; j < 4; ++j) bfr[j] = *(const bf16x8*)&Blds[(wn + j * 16 + l15) * BK + goff];
            #pragma unroll
            for (int i = 0; i < 4; ++i)
                #pragma unroll
                for (int j = 0; j < 4; ++j)
                    acc[i][j] = __builtin_amdgcn_mfma_f32_16x16x32_bf16(af[i], bfr[j], acc[i][j], 0, 0, 0);
        }
        __syncthreads();                       // all ds_reads done before re-staging
    }

    // epilogue: D element (row = q4*4+r, col = l15) within each 16x16 subtile
    #pragma unroll
    for (int i = 0; i < 4; ++i) {
        #pragma unroll
        for (int j = 0; j < 4; ++j) {
            #pragma unroll
            for (int r = 0; r < 4; ++r) {
                const int m = m0 + wm + i * 16 + q4 * 4 + r;
                const int n = n0 + wn + j * 16 + l15;
                const size_t off = (size_t)m * N + n;
                float c = acc[i][j][r];
                if (EPI == 0) {
                    ((unsigned short*)Cout)[off] = f2bf(c);
                } else if (EPI == 1) {
                    c += bias[n] + resid[off];
                    ((float*)Cout)[off] = c;
                } else if (EPI == 2) {
                    c += bias[n];
                    c = fmaxf(c, 0.f);
                    ((unsigned short*)Cout)[off] = f2bf(c);
                } else {
                    c += bias[n] + resid[off];
                    ((float*)Cout)[off] = c;
                }
            }
        }
    }
}

// ---------------- per-position differential attention: 1 wave / token --------
#define QKVS 3072
__global__ __launch_bounds__(256) void attn_pos(const unsigned short* __restrict__ qkv,
                                                const float* __restrict__ lq1,
                                                const float* __restrict__ lq2,
                                                const float* __restrict__ lk1,
                                                const float* __restrict__ lk2,
                                                unsigned short* __restrict__ outg)
{
    __shared__ __align__(16) float q2[4][32][36];
    __shared__ __align__(16) float k2[4][32][36];
    __shared__ __align__(16) float v2[4][16][64];
    __shared__ float att2[4][16][17];

    const int tid  = threadIdx.x;
    const int wave = tid >> 6;
    const int lane = tid & 63;
    const int pos  = blockIdx.x * 4 + wave;

    float s1 = 0.f, s2 = 0.f;
    #pragma unroll
    for (int i = 0; i < 32; ++i) {
        s1 += lq1[i] * lk1[i];
        s2 += lq2[i] * lk2[i];
    }
    const float lam = __expf(s1) - __expf(s2) + LAMBDA_INIT_F;

    const unsigned short* qrow = qkv + (size_t)pos * QKVS;
    const unsigned short* krow = qrow + DM;
    const unsigned short* vrow = qrow + 2 * DM;

    unsigned short tq[16], tk[16], tv[16];
    *(uint4*)&tq[0] = *(const uint4*)&qrow[lane * 16];
    *(uint4*)&tq[8] = *(const uint4*)&qrow[lane * 16 + 8];
    *(uint4*)&tk[0] = *(const uint4*)&krow[lane * 16];
    *(uint4*)&tk[8] = *(const uint4*)&krow[lane * 16 + 8];
    *(uint4*)&tv[0] = *(const uint4*)&vrow[lane * 16];
    *(uint4*)&tv[8] = *(const uint4*)&vrow[lane * 16 + 8];

    // channel c = h*64 + d*2 + qi -> q2[qi*16+h][d];  v: c = h*64+dd -> v2[h][dd]
    #pragma unroll
    for (int jj = 0; jj < 16; ++jj) {
        const int c  = lane * 16 + jj;
        const int h  = c >> 6;
        const int d  = (c >> 1) & 31;
        const int qi = c & 1;
        q2[wave][qi * 16 + h][d] = bf2f(tq[jj]) * QSCALE;
        k2[wave][qi * 16 + h][d] = bf2f(tk[jj]);
        v2[wave][c >> 6][c & 63] = bf2f(tv[jj]);
    }
    __syncthreads();

    const int qh = lane & 31, half = lane >> 5;
    float qreg[32];
    #pragma unroll
    for (int d4 = 0; d4 < 32; d4 += 4) {
        const f32x4 t = *(const f32x4*)&q2[wave][qh][d4];
        qreg[d4] = t[0]; qreg[d4+1] = t[1]; qreg[d4+2] = t[2]; qreg[d4+3] = t[3];
    }
    float p[16];
    #pragma unroll
    for (int jj = 0; jj < 16; ++jj) {
        const float* kr = &k2[wave][half * 16 + jj][0];
        float a = 0.f;
        #pragma unroll
        for (int d4 = 0; d4 < 32; d4 += 4) {
            const f32x4 kv = *(const f32x4*)&kr[d4];
            a += qreg[d4]*kv[0] + qreg[d4+1]*kv[1] + qreg[d4+2]*kv[2] + qreg[d4+3]*kv[3];
        }
        p[jj] = a;
    }

    float mx = p[0];
    #pragma unroll
    for (int jj = 1; jj < 16; ++jj) mx = fmaxf(mx, p[jj]);
    mx = fmaxf(mx, __shfl_xor(mx, 32));
    float sum = 0.f;
    #pragma unroll
    for (int jj = 0; jj < 16; ++jj) { p[jj] = __expf(p[jj] - mx); sum += p[jj]; }
    sum += __shfl_xor(sum, 32);
    const float inv = 1.0f / sum;

    if (half == 0 && qh < 16) {
        #pragma unroll
        for (int jj = 0; jj < 16; ++jj) att2[wave][qh][jj] = p[jj] * inv;
    }
    __syncthreads();
    if (half == 1 && qh >= 16) {
        const int a = qh - 16;
        #pragma unroll
        for (int jj = 0; jj < 16; ++jj) att2[wave][a][jj] -= lam * p[jj] * inv;
    }
    __syncthreads();

    const int a   = lane & 15;
    const int ddb = (lane >> 4) * 16;
    float areg[16];
    #pragma unroll
    for (int h = 0; h < 16; ++h) areg[h] = att2[wave][a][h];
    float o[16];
    #pragma unroll
    for (int j = 0; j < 16; ++j) o[j] = 0.f;
    #pragma unroll
    for (int h = 0; h < 16; ++h) {
        #pragma unroll
        for (int j4 = 0; j4 < 16; j4 += 4) {
            const f32x4 vv = *(const f32x4*)&v2[wave][h][ddb + j4];
            o[j4]   += areg[h] * vv[0];
            o[j4+1] += areg[h] * vv[1];
            o[j4+2] += areg[h] * vv[2];
            o[j4+3] += areg[h] * vv[3];
        }
    }

    float ss = 0.f;
    #pragma unroll
    for (int j = 0; j < 16; ++j) ss += o[j] * o[j];
    ss += __shfl_xor(ss, 16);
    ss += __shfl_xor(ss, 32);
    const float scl = rsqrtf(ss * (1.0f / 64.0f) + 1e-5f) * ONE_MINUS_LI;

    unsigned short ob[16];
    #pragma unroll
    for (int j = 0; j < 16; ++j) ob[j] = f2bf(o[j] * scl);
    unsigned short* orow = outg + (size_t)pos * DM + a * 64 + ddb;
    *(uint4*)&orow[0] = *(const uint4*)&ob[0];
    *(uint4*)&orow[8] = *(const uint4*)&ob[8];
}

// ---------------- launcher ----------------
extern "C" void kernel_launch(void* const* d_in, const int* in_sizes, int n_in,
                              void* d_out, int out_size, void* d_ws, size_t ws_size,
                              hipStream_t stream)
{
    const float* x   = (const float*)d_in[0];
    const float* Wq  = (const float*)d_in[1];
    const float* Wk  = (const float*)d_in[2];
    const float* Wv  = (const float*)d_in[3];
    const float* lq1 = (const float*)d_in[4];
    const float* lq2 = (const float*)d_in[5];
    const float* lk1 = (const float*)d_in[6];
    const float* lk2 = (const float*)d_in[7];
    const float* Wo  = (const float*)d_in[8];
    const float* bo  = (const float*)d_in[9];
    const float* g1  = (const float*)d_in[10];
    const float* be1 = (const float*)d_in[11];
    const float* g2  = (const float*)d_in[12];
    const float* be2 = (const float*)d_in[13];
    const float* W1  = (const float*)d_in[14];
    const float* b1  = (const float*)d_in[15];
    const float* W2  = (const float*)d_in[16];
    const float* b2  = (const float*)d_in[17];
    (void)in_sizes; (void)n_in; (void)out_size;

    const size_t MB = 1ull << 20;
    char* ws = (char*)d_ws;
    unsigned short* wqkv = (unsigned short*)(ws);             //  6 MB  [3072][1024] bf16
    unsigned short* wo   = (unsigned short*)(ws + 6 * MB);    //  2 MB
    unsigned short* w1   = (unsigned short*)(ws + 8 * MB);    //  8 MB
    unsigned short* w2   = (unsigned short*)(ws + 16 * MB);   //  8 MB
    unsigned short* h    = (unsigned short*)(ws + 24 * MB);   // 32 MB bf16, reused as attn-out
    unsigned short* qkv  = (unsigned short*)(ws + 56 * MB);   // 96 MB bf16 [16384][3072]
    float*          conn = (float*)(ws + 56 * MB);            // 64 MB f32 (over qkv, dead)
    unsigned short* attn = h;                                 // over h (dead)
    unsigned short* h2   = (unsigned short*)(ws + 120 * MB);  // 32 MB (over qkv tail, dead)
    unsigned short* t    = (unsigned short*)(ws + 152 * MB);  // FFN intermediate (chunked)

    int nch = 1;
    while (nch < 128 && 152 * MB + (size_t)(MROWS / nch) * FFDIM * 2 > ws_size) nch <<= 1;
    const int MC = MROWS / nch;

    const dim3 blk(256);

    cvt6_kernel<<<12288, blk, 0, stream>>>(Wq, Wk, Wv, Wo, W1, W2, wqkv, wo, w1, w2);

    ln_kernel<<<MROWS, blk, 0, stream>>>(x, g1, be1, h);

    gemm_bt<0><<<dim3(QKVS / 128, MROWS / 128), blk, 0, stream>>>(
        h, wqkv, qkv, nullptr, nullptr, MROWS, QKVS, DM);

    attn_pos<<<MROWS / 4, blk, 0, stream>>>(qkv, lq1, lq2, lk1, lk2, attn);

    gemm_bt<1><<<dim3(DM / 128, MROWS / 128), blk, 0, stream>>>(
        attn, wo, conn, bo, x, MROWS, DM, DM);

    ln_kernel<<<MROWS, blk, 0, stream>>>(conn, g2, be2, h2);

    for (int c = 0; c < nch; ++c) {
        const size_t roff = (size_t)c * MC;
        gemm_bt<2><<<dim3(FFDIM / 128, MC / 128), blk, 0, stream>>>(
            h2 + roff * DM, w1, t, b1, nullptr, MC, FFDIM, DM);
        gemm_bt<3><<<dim3(DM / 128, MC / 128), blk, 0, stream>>>(
            t, w2, (float*)d_out + roff * DM, b2, conn + roff * DM, MC, DM, FFDIM);
    }
}